// Round 5
// baseline (465.472 us; speedup 1.0000x reference)
//
#include <hip/hip_runtime.h>

// SpatialPool: fm [B=16, C=512, H=38, W=38] f32, replication pad 1,
// out[b, (h*W+w)*9*C + k*C + c] = fm[b, c, clamp(h+k/3-1), clamp(w+k%3-1)]
//
// R10: NT-FLAG A/B. Exoneration table so far (all kernels ~110-116us vs
// ~76us roofline): read bytes (R7), store placement/balance/XCD-pin (R8c),
// store width (R9: x4 stores, NEUTRAL vs dword) -- none is the limiter.
// The one constant across every ~110us variant: __builtin_nontemporal_store
// on all stores (adopted R6 for no-RFO, never A/B'd). Mechanism: nt bypasses
// L2 write aggregation and streams to HBM; fillBufferAligned hits 6.2 TB/s
// on this trace with PLAIN stores, and CDNA full-line wave stores don't RFO
// through TCC anyway -> nt may be all cost, no benefit.
// This kernel is byte-identical to R9 except nt stores -> plain stores.
// Predicted: if nt throttles, kernel 111 -> 75-90us (dur 454 -> 420-433);
// if flat +-2%, nt exonerated -> R11 restructures reads (LDS staging,
// wave-coalesced global loads).

#define BB 16
#define CC 512
#define HH 38
#define WW 38
#define HW (HH * WW)      // 1444
#define KK 9
#define NT 256

typedef float f32x2 __attribute__((ext_vector_type(2)));
typedef float f32x4 __attribute__((ext_vector_type(4)));

// 8 w-sub-ranges: ws -> covers w' in [W0, W0+WN); loads floats [WA, WA+2*NL)
// of each clamped row (always in-bounds, always covering clamp(W0-1..W0+WN)).
//   ws: 0:(0,5,0,3) 1:(5,5,4,4) 2:(10,5,8,4) 3:(15,4,14,3)
//       4:(19,5,18,4) 5:(24,5,22,4) 6:(29,5,28,4) 7:(34,4,32,3)
template <int W0, int WN, int WA, int NL>
__device__ __forceinline__ void do_sub(const float* __restrict__ fm,
                                       float* __restrict__ out,
                                       int b, int hp, int c0)
{
    const int r0 = (hp > 0) ? hp - 1 : 0;
    const int r2 = (hp < HH - 1) ? hp + 1 : HH - 1;
    const int rows[3] = { r0, hp, r2 };

    const float* p0 = fm + (size_t)(b * CC + c0 + 0) * HW;
    const float* p1 = fm + (size_t)(b * CC + c0 + 1) * HW;
    const float* p2 = fm + (size_t)(b * CC + c0 + 2) * HW;
    const float* p3 = fm + (size_t)(b * CC + c0 + 3) * HW;

    // vv[di][j] = input float (WA+j) of row di, packed across channels
    // c0..c0+3 in .x/.y/.z/.w -> ready-made f32x4 store operand.
    f32x4 vv[3][2 * NL];
    #pragma unroll
    for (int di = 0; di < 3; ++di) {
        const int ro = rows[di] * WW + WA;
        #pragma unroll
        for (int i = 0; i < NL; ++i) {
            const f32x2 t0 = *(const f32x2*)(p0 + ro + 2 * i);
            const f32x2 t1 = *(const f32x2*)(p1 + ro + 2 * i);
            const f32x2 t2 = *(const f32x2*)(p2 + ro + 2 * i);
            const f32x2 t3 = *(const f32x2*)(p3 + ro + 2 * i);
            vv[di][2 * i + 0] = (f32x4){t0.x, t1.x, t2.x, t3.x};
            vv[di][2 * i + 1] = (f32x4){t0.y, t1.y, t2.y, t3.y};
        }
    }

    // ---- stores: 16B/lane, wave = 1KB contiguous; PLAIN stores (L2
    // writeback/aggregation) -- the single toggle vs R9 ----
    float* outp = out + (size_t)((b * HW + hp * WW + W0) * KK) * CC + c0;
    #pragma unroll
    for (int wi = 0; wi < WN; ++wi) {
        #pragma unroll
        for (int di = 0; di < 3; ++di) {
            #pragma unroll
            for (int dj = 0; dj < 3; ++dj) {
                int wj = W0 + wi + dj - 1;             // compile-time under unroll
                wj = wj < 0 ? 0 : (wj > WW - 1 ? WW - 1 : wj);
                *(f32x4*)(outp + (size_t)(wi * KK + di * 3 + dj) * CC) =
                    vv[di][wj - WA];
            }
        }
    }
}

__global__ __launch_bounds__(NT) void spatial_pool_x4(
    const float* __restrict__ fm, float* __restrict__ out)
{
    // XCD pin: xcd = L&7 owns b in {xcd, xcd+8} (per-b input 2.95MB < 4MB L2)
    const unsigned L = blockIdx.x;          // 0..2431
    const int xcd  = (int)(L & 7u);
    const int slot = (int)(L >> 3);         // 0..303
    const int bsel = slot / 152;            // 0..1
    const int rem  = slot - bsel * 152;     // 0..151
    const int hp   = rem >> 2;              // 0..37
    const int qq   = rem & 3;               // 0..3
    const int b    = xcd + 8 * bsel;        // 0..15

    const int tid = (int)threadIdx.x;       // 0..255
    const int cg  = tid & 127;              // channel group
    const int sub = tid >> 7;               // 0..1, wave-uniform
    const int c0  = 4 * cg;
    const int ws  = qq * 2 + sub;           // 0..7, wave-uniform

    switch (ws) {
        case 0:  do_sub< 0, 5,  0, 3>(fm, out, b, hp, c0); break;
        case 1:  do_sub< 5, 5,  4, 4>(fm, out, b, hp, c0); break;
        case 2:  do_sub<10, 5,  8, 4>(fm, out, b, hp, c0); break;
        case 3:  do_sub<15, 4, 14, 3>(fm, out, b, hp, c0); break;
        case 4:  do_sub<19, 5, 18, 4>(fm, out, b, hp, c0); break;
        case 5:  do_sub<24, 5, 22, 4>(fm, out, b, hp, c0); break;
        case 6:  do_sub<29, 5, 28, 4>(fm, out, b, hp, c0); break;
        default: do_sub<34, 4, 32, 3>(fm, out, b, hp, c0); break;
    }
}

extern "C" void kernel_launch(void* const* d_in, const int* in_sizes, int n_in,
                              void* d_out, int out_size, void* d_ws, size_t ws_size,
                              hipStream_t stream) {
    const float* fm = (const float*)d_in[0];
    float* out = (float*)d_out;
    dim3 grid(BB * HH * 4);   // 2432 blocks = 8 XCDs x 304
    dim3 block(NT);
    spatial_pool_x4<<<grid, block, 0, stream>>>(fm, out);
}

// Round 7
// 449.237 us; speedup vs baseline: 1.0361x; 1.0361x over previous
//
#include <hip/hip_runtime.h>

// SpatialPool: fm [B=16, C=512, H=38, W=38] f32, replication pad 1,
// out[b, (h*W+w)*9*C + k*C + c] = fm[b, c, clamp(h+k/3-1), clamp(w+k%3-1)]
//
// R11b: infra retry of R11 (round-6 "container failed twice" = acquire/push
// failure, kernel never executed; OOB re-audit clean: load end == plane end,
// store end == buffer end). Only change: quarter index from HIGH bits of
// blockIdx (cosmetic binary reshuffle -- same hedge that got R8c through).
//
// R11: PURE STREAMING, provably-minimal traffic, zero cache assumptions.
// History: R7 scatter 110us, R8c gather+pin 116, R9 x4 stores 111,
// R10 plain stores 120 (nt wins, restored). All ~equal -> the one property
// never provably achieved is minimal FETCH (last measured: 165MB = 3.5x).
//  - READ-ONCE by construction: block=(b,h,wquarter), thread=4-ch group,
//    reads ONLY its own w-window of row h (no halo, quarters disjoint) ->
//    every input float loaded exactly once device-wide. FETCH floor 47.3MB
//    independent of XCD mapping / L2 retention. Swizzle dropped (no reuse).
//  - Scatter x4 nt stores (R9/R10 verdicts): wave = 1KB contiguous per
//    (w',k) chunk; each output line written exactly once.
//  - FULL RESIDENCY: 2432 blocks x 2 waves = 4864 waves, VGPR ~64-96 ->
//    8 waves/SIMD -> all co-resident (cap 8192). Uniform per-thread work
//    (3 hrow x 3 woff always; R7-verified clamp rebalance).
// Predicted: FETCH 47-55MB, WRITE 426MB, kernel 111 -> 85-95us
// (dur ~428-440). If flat ~110 (dur 452-465): mixed-stream floor ->
// ROOFLINE next round.

#define BB 16
#define CC 512
#define HH 38
#define WW 38
#define HW (HH * WW)      // 1444
#define KK 9
#define NT 128

typedef float f32x2 __attribute__((ext_vector_type(2)));
typedef float f32x4 __attribute__((ext_vector_type(4)));

// Quarter q covers source w in [W0, W0+WN): (0,10) (10,10) (20,10) (30,8).
template <int W0, int WN>
__device__ __forceinline__ void do_q(const float* __restrict__ fm,
                                     float* __restrict__ out,
                                     int b, int h, int c0)
{
    // ---- 3 output-row targets (absolute (b*HW + hp*WW)*9 + di*3), exactly 3 ----
    int hrow[3];
    {
        int n = 0;
        #pragma unroll
        for (int di = 0; di < 3; ++di) {
            int hm = h + 1 - di;
            if (0 <= hm && hm < HH) { hrow[n] = (b * HW + hm * WW) * KK + di * 3; n++; }
        }
        if (h == 0)      { hrow[n] = (b * HW) * KK; n++; }                      // di=0,hp=0
        if (h == HH - 1) { hrow[n] = (b * HW + (HH - 1) * WW) * KK + 6; n++; }  // di=2,hp=37
    }

    const float* p0 = fm + (size_t)(b * CC + c0 + 0) * HW + h * WW + W0;
    const float* p1 = p0 + HW;
    const float* p2 = p0 + 2 * HW;
    const float* p3 = p0 + 3 * HW;
    float* ob = out + c0;

    // ---- w-pair interleaved: load 4 planes' f32x2, pack 2 x4, 18 stores ----
    #pragma unroll
    for (int i2 = 0; i2 < WN / 2; ++i2) {
        const f32x2 t0 = *(const f32x2*)(p0 + 2 * i2);
        const f32x2 t1 = *(const f32x2*)(p1 + 2 * i2);
        const f32x2 t2 = *(const f32x2*)(p2 + 2 * i2);
        const f32x2 t3 = *(const f32x2*)(p3 + 2 * i2);
        const f32x4 va = (f32x4){t0.x, t1.x, t2.x, t3.x};
        const f32x4 vb = (f32x4){t0.y, t1.y, t2.y, t3.y};

        #pragma unroll
        for (int par = 0; par < 2; ++par) {
            const int w = W0 + 2 * i2 + par;       // compile-time under unroll
            const f32x4 val = par ? vb : va;
            // exactly 3 w-targets (compile-time consts)
            int woff[3];
            int m = 0;
            #pragma unroll
            for (int dj = 0; dj < 3; ++dj) {
                int wm = w + 1 - dj;
                if (0 <= wm && wm < WW) { woff[m] = wm * KK + dj; m++; }
            }
            if (w == 0)      { woff[m] = 0; m++; }
            if (w == WW - 1) { woff[m] = (WW - 1) * KK + 2; m++; }

            #pragma unroll
            for (int i = 0; i < 3; ++i) {
                #pragma unroll
                for (int j = 0; j < 3; ++j) {
                    const unsigned idx = (unsigned)(hrow[i] + woff[j]) * (unsigned)CC;
                    __builtin_nontemporal_store(val, (f32x4*)(ob + (size_t)idx));
                }
            }
        }
    }
}

__global__ __launch_bounds__(NT) void spatial_pool_stream(
    const float* __restrict__ fm, float* __restrict__ out)
{
    const unsigned L = blockIdx.x;          // 0..2431
    const int q  = (int)(L / 608u);         // 0..3 (quarter in HIGH bits now)
    const int bh = (int)(L - 608u * q);     // 0..607
    const int h  = bh % HH;
    const int b  = bh / HH;
    const int c0 = 4 * (int)threadIdx.x;    // 0..508

    switch (q) {
        case 0:  do_q< 0, 10>(fm, out, b, h, c0); break;
        case 1:  do_q<10, 10>(fm, out, b, h, c0); break;
        case 2:  do_q<20, 10>(fm, out, b, h, c0); break;
        default: do_q<30,  8>(fm, out, b, h, c0); break;
    }
}

extern "C" void kernel_launch(void* const* d_in, const int* in_sizes, int n_in,
                              void* d_out, int out_size, void* d_ws, size_t ws_size,
                              hipStream_t stream) {
    const float* fm = (const float*)d_in[0];
    float* out = (float*)d_out;
    dim3 grid(BB * HH * 4);   // 2432 blocks x 128 thr = 4864 waves, all resident
    dim3 block(NT);
    spatial_pool_stream<<<grid, block, 0, stream>>>(fm, out);
}